// Round 1
// baseline (34111.591 us; speedup 1.0000x reference)
//
#include <hip/hip_runtime.h>
#include <hip/hip_bf16.h>
#include <math.h>

// Problem constants
#define SEQL   4096
#define NITEMS 512
#define HID    256
#define NLAY   16
#define QS     64      // ring slots (power of 2)
#define TPB    4       // timesteps per block in proj kernel

// Workspace layout (float offsets)
#define P_OFF   ((size_t)0)                               // P[4][SEQL][HID]
#define H_OFF   (P_OFF + (size_t)4*SEQL*HID)              // Hring[4][NLAY][QS][HID]
#define AP_OFF  (H_OFF + (size_t)4*NLAY*QS*HID)           // Apart[4][NLAY][2][QS][HID]
#define HF_OFF  (AP_OFF + (size_t)4*NLAY*2*QS*HID)        // hfinal[4][HID]
#define FLAG_OFF_FLOATS (HF_OFF + (size_t)1024)
// flags: Hflag[64] | Aflag[128] | progA[128] | progB[64]  => 384 u32
#define NFLAGS 384

// ---------------------------------------------------------------------------
// Spin helper: tid0-only, sticky timeout so bugs terminate instead of hanging.
__device__ __forceinline__ void spin_ge(const unsigned* p, unsigned target, bool* dead) {
    if (*dead) return;
    unsigned it = 0;
    while (__hip_atomic_load(p, __ATOMIC_RELAXED, __HIP_MEMORY_SCOPE_AGENT) < target) {
        __builtin_amdgcn_s_sleep(2);
        if (++it > (1u << 22)) { *dead = true; return; }
    }
}

// ---------------------------------------------------------------------------
// Kernel 1: input projection P[c][t][j] = sum_k Wih0_c[j,k] * x[t,k,c]
// (biases are added later in the B-stage; P is the pure projection)
__global__ __launch_bounds__(1024) void proj_kernel(
    const float* __restrict__ x, const float* __restrict__ Wlp,
    const float* __restrict__ Wlpv, float* __restrict__ P)
{
    __shared__ float xs[TPB][4][NITEMS];   // [tt][chain][k]  = 32 KB
    const int tid = threadIdx.x;
    const int t0 = blockIdx.x * TPB;

    #pragma unroll
    for (int tt = 0; tt < TPB; ++tt) {
        const float2* src = (const float2*)(x + (size_t)(t0 + tt) * NITEMS * 4);
        float2 v = src[tid];
        int e = 2 * tid;                    // e even -> (e&3) in {0,2}; e+1 same k
        xs[tt][e & 3][e >> 2]       = v.x;
        xs[tt][(e + 1) & 3][e >> 2] = v.y;
    }
    __syncthreads();

    const int c = tid >> 8, j = tid & 255;
    const float* W = (c == 1) ? Wlpv : Wlp;
    const float4* row = (const float4*)(W + (size_t)j * NITEMS);
    float acc[TPB] = {0.f, 0.f, 0.f, 0.f};
    #pragma unroll 4
    for (int k4 = 0; k4 < NITEMS / 4; ++k4) {
        float4 w = row[k4];
        #pragma unroll
        for (int tt = 0; tt < TPB; ++tt) {
            float4 xv = *(const float4*)(&xs[tt][c][k4 * 4]);
            acc[tt] = fmaf(w.x, xv.x, fmaf(w.y, xv.y, fmaf(w.z, xv.z, fmaf(w.w, xv.w, acc[tt]))));
        }
    }
    #pragma unroll
    for (int tt = 0; tt < TPB; ++tt)
        P[((size_t)c * SEQL + (t0 + tt)) * HID + j] = acc[tt];
}

// ---------------------------------------------------------------------------
// Kernel 2: layer-pipelined RNN. 184 blocks = 4 chains x (1 B0 + 15 x (B + 2A)).
// B(c,l): holds Whh[l] in regs (64 f/thread), owns the recurrence (h in LDS),
//         combines A-partials (+P for l==0) + bias, tanh, publishes h.
// A(c,l,s): holds Wih[l-1][:, 128s:128s+128] in regs (32 f/thread), consumes
//         h_{l-1}(t) from the ring, publishes its partial.
__global__ __launch_bounds__(1024) void rnn_pipe(
    const float* __restrict__ lp_Wih,  const float* __restrict__ lp_Whh,
    const float* __restrict__ lp_bih,  const float* __restrict__ lp_bhh,
    const float* __restrict__ lpv_Wih, const float* __restrict__ lpv_Whh,
    const float* __restrict__ lpv_bih, const float* __restrict__ lpv_bhh,
    const float* __restrict__ P, float* __restrict__ Hring,
    float* __restrict__ Apart, float* __restrict__ hfinal,
    unsigned* __restrict__ Hflag, unsigned* __restrict__ Aflag,
    unsigned* __restrict__ progA, unsigned* __restrict__ progB)
{
    __shared__ float hbuf[HID];     // this stage's h(t-1)
    __shared__ float part[1024];    // K-chunk partial sums

    const int b = blockIdx.x;
    if (b >= 184) return;
    const int c = b / 46;
    const int r = b % 46;
    int l, role, s = 0;             // role 0 = B, 1 = A
    if (r == 0) { l = 0; role = 0; }
    else { l = (r - 1) / 3 + 1; int q = (r - 1) % 3; role = (q == 0) ? 0 : 1; s = q - 1; }

    const float* Wih = (c == 1) ? lpv_Wih : lp_Wih;
    const float* Whh = (c == 1) ? lpv_Whh : lp_Whh;
    const float* bih = (c == 1) ? lpv_bih : lp_bih;
    const float* bhh = (c == 1) ? lpv_bhh : lp_bhh;

    const int tid = threadIdx.x;
    const int j = tid & 255, c4 = tid >> 8;
    bool dead = false;

    if (role == 0) {
        // ===================== B role =====================
        float wh[64];
        const float* wrow = Whh + ((size_t)l * HID + j) * HID + (size_t)c4 * 64;
        #pragma unroll
        for (int i = 0; i < 16; ++i) {
            float4 v = ((const float4*)wrow)[i];
            wh[4*i+0] = v.x; wh[4*i+1] = v.y; wh[4*i+2] = v.z; wh[4*i+3] = v.w;
        }
        const float bias = bih[l * HID + j] + bhh[l * HID + j];

        const float*    Psrc  = P + (size_t)c * SEQL * HID;
        const float*    ap0   = Apart + (((size_t)(c*NLAY + l)*2 + 0) * QS) * HID;
        const float*    ap1   = Apart + (((size_t)(c*NLAY + l)*2 + 1) * QS) * HID;
        const unsigned* af0   = Aflag + (c*NLAY + l)*2 + 0;
        const unsigned* af1   = Aflag + (c*NLAY + l)*2 + 1;
        unsigned*       myHfl = Hflag + c*NLAY + l;
        unsigned*       myprg = progB + c*NLAY + l;
        const unsigned* cons0 = progA + (c*NLAY + (l+1))*2 + 0;   // valid when l<15
        const unsigned* cons1 = progA + (c*NLAY + (l+1))*2 + 1;
        float*          Hout  = Hring + ((size_t)(c*NLAY + l) * QS) * HID;
        float*          hfin  = hfinal + (size_t)c * HID;

        if (tid < HID) hbuf[tid] = 0.f;
        __syncthreads();

        for (int t = 0; t < SEQL; ++t) {
            const int slot = t & (QS - 1);
            if (l > 0) {
                if (tid == 0) { spin_ge(af0, t+1, &dead); spin_ge(af1, t+1, &dead); __threadfence(); }
                __syncthreads();
            }
            // issue partial loads early; latency hides under the Whh FMA loop
            float a0 = 0.f, a1 = 0.f;
            if (tid < HID) {
                if (l == 0) a0 = Psrc[(size_t)t * HID + tid];
                else { a0 = ap0[(size_t)slot * HID + tid]; a1 = ap1[(size_t)slot * HID + tid]; }
            }
            // Whh * h(t-1): LDS broadcast reads (same addr per wave) + reg weights
            float acc0 = 0.f, acc1 = 0.f;
            const float4* hb4 = (const float4*)hbuf;
            #pragma unroll
            for (int i = 0; i < 16; ++i) {
                float4 v = hb4[c4 * 16 + i];
                if (i & 1) {
                    acc1 = fmaf(wh[4*i+0], v.x, acc1); acc1 = fmaf(wh[4*i+1], v.y, acc1);
                    acc1 = fmaf(wh[4*i+2], v.z, acc1); acc1 = fmaf(wh[4*i+3], v.w, acc1);
                } else {
                    acc0 = fmaf(wh[4*i+0], v.x, acc0); acc0 = fmaf(wh[4*i+1], v.y, acc0);
                    acc0 = fmaf(wh[4*i+2], v.z, acc0); acc0 = fmaf(wh[4*i+3], v.w, acc0);
                }
            }
            part[tid] = acc0 + acc1;
            __syncthreads();
            if (tid < HID) {
                float tot = part[tid] + part[tid+256] + part[tid+512] + part[tid+768]
                          + a0 + a1 + bias;
                float h = tanhf(tot);
                hbuf[tid] = h;
                if (l < NLAY - 1) Hout[(size_t)slot * HID + tid] = h;
                if (l == NLAY - 1 && t == SEQL - 1) hfin[tid] = h;
            }
            __syncthreads();   // drains stores (vmcnt 0) + hbuf visible for next iter
            if (tid == 0) {
                if (l < NLAY - 1) {
                    __threadfence();
                    __hip_atomic_store(myHfl, (unsigned)(t+1), __ATOMIC_RELAXED, __HIP_MEMORY_SCOPE_AGENT);
                    if (t >= QS - 8 && t < SEQL - 1) {   // ring back-pressure
                        unsigned tgt = (unsigned)(t - QS + 9);
                        spin_ge(cons0, tgt, &dead);
                        spin_ge(cons1, tgt, &dead);
                    }
                }
                if (l > 0 && (t & 7) == 0)
                    __hip_atomic_store(myprg, (unsigned)(t+1), __ATOMIC_RELAXED, __HIP_MEMORY_SCOPE_AGENT);
            }
        }
    } else {
        // ===================== A role =====================
        float wi[32];
        const float* wrow = Wih + ((size_t)(l-1) * HID + j) * HID + (size_t)s * 128 + (size_t)c4 * 32;
        #pragma unroll
        for (int i = 0; i < 8; ++i) {
            float4 v = ((const float4*)wrow)[i];
            wi[4*i+0] = v.x; wi[4*i+1] = v.y; wi[4*i+2] = v.z; wi[4*i+3] = v.w;
        }
        const float*    Hin    = Hring + ((size_t)(c*NLAY + (l-1)) * QS) * HID;
        const unsigned* inflag = Hflag + c*NLAY + (l-1);
        float*          Aout   = Apart + (((size_t)(c*NLAY + l)*2 + s) * QS) * HID;
        unsigned*       myflag = Aflag + (c*NLAY + l)*2 + s;
        unsigned*       myprog = progA + (c*NLAY + l)*2 + s;
        const unsigned* conspg = progB + c*NLAY + l;

        // prologue: prefetch h(0)
        if (tid == 0) { spin_ge(inflag, 1u, &dead); __threadfence(); }
        __syncthreads();
        float4 iv[8];
        {
            const float4* src = (const float4*)(Hin + (size_t)s * 128 + (size_t)c4 * 32);
            #pragma unroll
            for (int i = 0; i < 8; ++i) iv[i] = src[i];
        }

        for (int t = 0; t < SEQL; ++t) {
            const int slot = t & (QS - 1);
            float acc0 = 0.f, acc1 = 0.f;
            #pragma unroll
            for (int i = 0; i < 8; ++i) {
                float4 v = iv[i];
                if (i & 1) {
                    acc1 = fmaf(wi[4*i+0], v.x, acc1); acc1 = fmaf(wi[4*i+1], v.y, acc1);
                    acc1 = fmaf(wi[4*i+2], v.z, acc1); acc1 = fmaf(wi[4*i+3], v.w, acc1);
                } else {
                    acc0 = fmaf(wi[4*i+0], v.x, acc0); acc0 = fmaf(wi[4*i+1], v.y, acc0);
                    acc0 = fmaf(wi[4*i+2], v.z, acc0); acc0 = fmaf(wi[4*i+3], v.w, acc0);
                }
            }
            // prefetch h(t+1): loads fly while we reduce/publish step t
            if (t + 1 < SEQL) {
                if (tid == 0) { spin_ge(inflag, (unsigned)(t+2), &dead); __threadfence(); }
                __syncthreads();
                const float4* src = (const float4*)(Hin + (size_t)((t+1) & (QS-1)) * HID
                                                    + (size_t)s * 128 + (size_t)c4 * 32);
                #pragma unroll
                for (int i = 0; i < 8; ++i) iv[i] = src[i];
            }
            part[tid] = acc0 + acc1;
            __syncthreads();
            if (tid < HID) {
                float tot = part[tid] + part[tid+256] + part[tid+512] + part[tid+768];
                Aout[(size_t)slot * HID + tid] = tot;
            }
            __syncthreads();   // drain partial stores before flag
            if (tid == 0) {
                __threadfence();
                __hip_atomic_store(myflag, (unsigned)(t+1), __ATOMIC_RELAXED, __HIP_MEMORY_SCOPE_AGENT);
                if ((t & 7) == 0)
                    __hip_atomic_store(myprog, (unsigned)(t+1), __ATOMIC_RELAXED, __HIP_MEMORY_SCOPE_AGENT);
                if (t >= QS - 8 && t < SEQL - 1)
                    spin_ge(conspg, (unsigned)(t - QS + 9), &dead);
            }
        }
    }
}

// ---------------------------------------------------------------------------
// Kernel 3: out = fc_W @ concat(h0..h3) + fc_b    (2 outputs)
__global__ __launch_bounds__(1024) void fc_kernel(
    const float* __restrict__ hfinal, const float* __restrict__ fcW,
    const float* __restrict__ fcb, float* __restrict__ out)
{
    __shared__ float red[1024];
    const int tid = threadIdx.x;
    float v  = hfinal[tid];                 // concat order = chain order 0..3
    float p0 = fcW[tid] * v;
    float p1 = fcW[1024 + tid] * v;

    red[tid] = p0; __syncthreads();
    for (int st = 512; st > 0; st >>= 1) { if (tid < st) red[tid] += red[tid + st]; __syncthreads(); }
    if (tid == 0) out[0] = red[0] + fcb[0];
    __syncthreads();
    red[tid] = p1; __syncthreads();
    for (int st = 512; st > 0; st >>= 1) { if (tid < st) red[tid] += red[tid + st]; __syncthreads(); }
    if (tid == 0) out[1] = red[0] + fcb[1];
}

// ---------------------------------------------------------------------------
extern "C" void kernel_launch(void* const* d_in, const int* in_sizes, int n_in,
                              void* d_out, int out_size, void* d_ws, size_t ws_size,
                              hipStream_t stream)
{
    (void)in_sizes; (void)n_in; (void)out_size; (void)ws_size;
    const float* x        = (const float*)d_in[0];
    const float* lp_Wih0  = (const float*)d_in[1];
    const float* lp_Wih   = (const float*)d_in[2];
    const float* lp_Whh   = (const float*)d_in[3];
    const float* lp_bih   = (const float*)d_in[4];
    const float* lp_bhh   = (const float*)d_in[5];
    const float* lpv_Wih0 = (const float*)d_in[6];
    const float* lpv_Wih  = (const float*)d_in[7];
    const float* lpv_Whh  = (const float*)d_in[8];
    const float* lpv_bih  = (const float*)d_in[9];
    const float* lpv_bhh  = (const float*)d_in[10];
    const float* fcW      = (const float*)d_in[11];
    const float* fcb      = (const float*)d_in[12];

    float* ws      = (float*)d_ws;
    float* Pbuf    = ws + P_OFF;
    float* Hring   = ws + H_OFF;
    float* Apart   = ws + AP_OFF;
    float* hfinal  = ws + HF_OFF;
    unsigned* flags = (unsigned*)(ws + FLAG_OFF_FLOATS);

    hipMemsetAsync(flags, 0, NFLAGS * sizeof(unsigned), stream);

    proj_kernel<<<SEQL / TPB, 1024, 0, stream>>>(x, lp_Wih0, lpv_Wih0, Pbuf);

    rnn_pipe<<<184, 1024, 0, stream>>>(lp_Wih, lp_Whh, lp_bih, lp_bhh,
                                       lpv_Wih, lpv_Whh, lpv_bih, lpv_bhh,
                                       Pbuf, Hring, Apart, hfinal,
                                       flags, flags + 64, flags + 192, flags + 320);

    fc_kernel<<<1, 1024, 0, stream>>>(hfinal, fcW, fcb, (float*)d_out);
}

// Round 2
// 9012.068 us; speedup vs baseline: 3.7851x; 3.7851x over previous
//
#include <hip/hip_runtime.h>
#include <hip/hip_bf16.h>
#include <math.h>

// Problem constants
#define SEQL   4096
#define NITEMS 512
#define HID    256
#define NLAY   16
#define QS     64      // ring slots (power of 2)
#define TPB    4       // timesteps per block in proj kernel

// Workspace layout (float offsets)
#define P_OFF   ((size_t)0)                               // P[4][SEQL][HID]
#define H_OFF   (P_OFF + (size_t)4*SEQL*HID)              // Hring[4][NLAY][QS][HID]
#define AP_OFF  (H_OFF + (size_t)4*NLAY*QS*HID)           // Apart[4][NLAY][QS][HID]
#define HF_OFF  (AP_OFF + (size_t)4*NLAY*QS*HID)          // hfinal[4][HID]
#define FLAG_OFF_FLOATS (HF_OFF + (size_t)1024)
// flags: Hflag[64] | Aflag[64] | progA[64] | progB[64]  => 256 u32
#define NFLAGS 256

// ---------------------------------------------------------------------------
// Agent-scope (Infinity-Cache-coherent) accessors. These bypass the
// non-coherent per-XCD L2s entirely -> NO fences needed anywhere.
__device__ __forceinline__ float gload(const float* p) {
    return __hip_atomic_load(p, __ATOMIC_RELAXED, __HIP_MEMORY_SCOPE_AGENT);
}
__device__ __forceinline__ void gstore(float* p, float v) {
    __hip_atomic_store(p, v, __ATOMIC_RELAXED, __HIP_MEMORY_SCOPE_AGENT);
}
__device__ __forceinline__ unsigned uload(const unsigned* p) {
    return __hip_atomic_load(p, __ATOMIC_RELAXED, __HIP_MEMORY_SCOPE_AGENT);
}
__device__ __forceinline__ void ustore(unsigned* p, unsigned v) {
    __hip_atomic_store(p, v, __ATOMIC_RELAXED, __HIP_MEMORY_SCOPE_AGENT);
}

// Spin until *p >= target. Sticky timeout -> bugs give wrong answers, not hangs.
__device__ __forceinline__ unsigned spin_ge(const unsigned* p, unsigned target, bool* dead) {
    unsigned v = uload(p);
    if (v >= target || *dead) return v;
    unsigned it = 0;
    while ((v = uload(p)) < target) {
        __builtin_amdgcn_s_sleep(2);
        if (++it > (1u << 20)) { *dead = true; break; }
    }
    return v;
}

// ---------------------------------------------------------------------------
// Kernel 1: input projection P[c][t][j] = sum_k Wih0_c[j,k] * x[t,k,c]
__global__ __launch_bounds__(1024) void proj_kernel(
    const float* __restrict__ x, const float* __restrict__ Wlp,
    const float* __restrict__ Wlpv, float* __restrict__ P)
{
    __shared__ float xs[TPB][4][NITEMS];   // 32 KB
    const int tid = threadIdx.x;
    const int t0 = blockIdx.x * TPB;

    #pragma unroll
    for (int tt = 0; tt < TPB; ++tt) {
        const float2* src = (const float2*)(x + (size_t)(t0 + tt) * NITEMS * 4);
        float2 v = src[tid];
        int e = 2 * tid;
        xs[tt][e & 3][e >> 2]       = v.x;
        xs[tt][(e + 1) & 3][e >> 2] = v.y;
    }
    __syncthreads();

    const int c = tid >> 8, j = tid & 255;
    const float* W = (c == 1) ? Wlpv : Wlp;
    const float4* row = (const float4*)(W + (size_t)j * NITEMS);
    float acc[TPB] = {0.f, 0.f, 0.f, 0.f};
    #pragma unroll 4
    for (int k4 = 0; k4 < NITEMS / 4; ++k4) {
        float4 w = row[k4];
        #pragma unroll
        for (int tt = 0; tt < TPB; ++tt) {
            float4 xv = *(const float4*)(&xs[tt][c][k4 * 4]);
            acc[tt] = fmaf(w.x, xv.x, fmaf(w.y, xv.y, fmaf(w.z, xv.z, fmaf(w.w, xv.w, acc[tt]))));
        }
    }
    #pragma unroll
    for (int tt = 0; tt < TPB; ++tt)
        P[((size_t)c * SEQL + (t0 + tt)) * HID + j] = acc[tt];
}

// ---------------------------------------------------------------------------
// Kernel 2: layer-pipelined RNN. 124 blocks = 4 chains x (16 B + 15 A).
// B(c,l): Whh[l] in VGPRs (64/thr), owns recurrence (h in LDS), combines the
//         A partial (or P for l==0) + bias, tanh, publishes h via IF$.
// A(c,l) l>=1: Wih[l-1] in VGPRs (64/thr), consumes h_{l-1}(t), publishes the
//         full Wih@h partial via IF$.
// All handshakes: relaxed agent atomics, software-pipelined 2 steps ahead.
__global__ __launch_bounds__(1024) void rnn_pipe(
    const float* __restrict__ lp_Wih,  const float* __restrict__ lp_Whh,
    const float* __restrict__ lp_bih,  const float* __restrict__ lp_bhh,
    const float* __restrict__ lpv_Wih, const float* __restrict__ lpv_Whh,
    const float* __restrict__ lpv_bih, const float* __restrict__ lpv_bhh,
    const float* __restrict__ P, float* __restrict__ Hring,
    float* __restrict__ Apart, float* __restrict__ hfinal,
    unsigned* __restrict__ Hflag, unsigned* __restrict__ Aflag,
    unsigned* __restrict__ progA, unsigned* __restrict__ progB)
{
    __shared__ float hh[2][HID];    // B: hh[0] = h(t-1).  A: double-buffered input.
    __shared__ float part[1024];

    const int b = blockIdx.x;
    if (b >= 124) return;
    const int c = b / 31;
    const int r = b % 31;
    const int role = (r < NLAY) ? 0 : 1;            // 0 = B, 1 = A
    const int l = (r < NLAY) ? r : (r - NLAY + 1);  // A covers l = 1..15

    const float* Wih = (c == 1) ? lpv_Wih : lp_Wih;
    const float* Whh = (c == 1) ? lpv_Whh : lp_Whh;
    const float* bih = (c == 1) ? lpv_bih : lp_bih;
    const float* bhh = (c == 1) ? lpv_bhh : lp_bhh;

    const int tid = threadIdx.x;
    const int j = tid & 255, c4 = tid >> 8;   // c4 is wave-uniform
    bool dead = false;

    if (role == 0) {
        // ===================== B role =====================
        float wh[64];
        {
            const float4* wrow = (const float4*)(Whh + ((size_t)l * HID + j) * HID + (size_t)c4 * 64);
            #pragma unroll
            for (int i = 0; i < 16; ++i) {
                float4 v = wrow[i];
                wh[4*i+0] = v.x; wh[4*i+1] = v.y; wh[4*i+2] = v.z; wh[4*i+3] = v.w;
            }
        }
        #pragma unroll
        for (int i = 0; i < 64; ++i) asm volatile("" : "+v"(wh[i]));  // pin in VGPRs
        const float bias = bih[l * HID + j] + bhh[l * HID + j];

        const float*    Psrc     = P + (size_t)c * SEQL * HID;
        const float*    ap       = Apart + ((size_t)(c*NLAY + l) * QS) * HID;
        const unsigned* af       = Aflag + c*NLAY + l;
        unsigned*       myHfl    = Hflag + c*NLAY + l;
        unsigned*       myprogB  = progB + c*NLAY + l;
        const unsigned* consProgA= progA + c*NLAY + (l+1);   // valid when l<15
        float*          Hout     = Hring + ((size_t)(c*NLAY + l) * QS) * HID;
        float*          hfin     = hfinal + (size_t)c * HID;

        if (tid < HID) hh[0][tid] = 0.f;
        if (l > 0 && tid == 0) spin_ge(af, 1u, &dead);       // partial(0) ready
        __syncthreads();

        unsigned progA_seen = 0;
        for (int t = 0; t < SEQL; ++t) {
            const int slot = t & (QS - 1);
            // issue partial load for step t (flag confirmed previous iter)
            float a0 = 0.f;
            if (tid < HID)
                a0 = (l == 0) ? Psrc[(size_t)t * HID + tid]
                              : gload(ap + (size_t)slot * HID + tid);
            // issue next-step flag probe (checked later, overlapped with FMA)
            unsigned afv = 0xFFFFFFFFu;
            if (l > 0 && tid == 0) afv = uload(af);
            // ring back-pressure gate (rare; gates the stores via barrier below)
            if (tid == 0 && l < NLAY-1 && (t & 7) == 0 && t + 8 > QS) {
                unsigned need = (unsigned)(t + 8 - QS);
                if (progA_seen < need) progA_seen = spin_ge(consProgA, need, &dead);
            }
            // Whh * h(t-1): LDS broadcast + register weights
            float acc0 = 0.f, acc1 = 0.f;
            const float4* hb4 = (const float4*)hh[0];
            #pragma unroll
            for (int i = 0; i < 16; ++i) {
                float4 v = hb4[c4 * 16 + i];
                if (i & 1) {
                    acc1 = fmaf(wh[4*i+0], v.x, acc1); acc1 = fmaf(wh[4*i+1], v.y, acc1);
                    acc1 = fmaf(wh[4*i+2], v.z, acc1); acc1 = fmaf(wh[4*i+3], v.w, acc1);
                } else {
                    acc0 = fmaf(wh[4*i+0], v.x, acc0); acc0 = fmaf(wh[4*i+1], v.y, acc0);
                    acc0 = fmaf(wh[4*i+2], v.z, acc0); acc0 = fmaf(wh[4*i+3], v.w, acc0);
                }
            }
            part[tid] = acc0 + acc1;
            __syncthreads();
            if (tid < HID) {
                float tot = part[tid] + part[tid+256] + part[tid+512] + part[tid+768]
                          + a0 + bias;
                float h = tanhf(tot);
                hh[0][tid] = h;
                if (l < NLAY - 1) gstore(Hout + (size_t)slot * HID + tid, h);
                else if (t == SEQL - 1) gstore(hfin + tid, h);
            }
            if (tid == 0) {
                if (l > 0 && t + 1 < SEQL && afv < (unsigned)(t + 2))
                    spin_ge(af, (unsigned)(t + 2), &dead);   // ensure next iter's load legal
                if (l > 0 && (t & 7) == 7) ustore(myprogB, (unsigned)(t + 1));
            }
            __syncthreads();   // drains IF$ stores (vmcnt) before flag
            if (tid == 0 && l < NLAY - 1) ustore(myHfl, (unsigned)(t + 1));
        }
    } else {
        // ===================== A role =====================
        float wi[64];
        {
            const float4* wrow = (const float4*)(Wih + ((size_t)(l-1) * HID + j) * HID + (size_t)c4 * 64);
            #pragma unroll
            for (int i = 0; i < 16; ++i) {
                float4 v = wrow[i];
                wi[4*i+0] = v.x; wi[4*i+1] = v.y; wi[4*i+2] = v.z; wi[4*i+3] = v.w;
            }
        }
        #pragma unroll
        for (int i = 0; i < 64; ++i) asm volatile("" : "+v"(wi[i]));  // pin in VGPRs

        const float*    Hin      = Hring + ((size_t)(c*NLAY + (l-1)) * QS) * HID;
        const unsigned* inflag   = Hflag + c*NLAY + (l-1);
        float*          Aout     = Apart + ((size_t)(c*NLAY + l) * QS) * HID;
        unsigned*       myflag   = Aflag + c*NLAY + l;
        unsigned*       myprogA  = progA + c*NLAY + l;
        const unsigned* consProgB= progB + c*NLAY + l;

        // prologue: h(0) into hh[0], and confirm h(1) published
        if (tid == 0) spin_ge(inflag, 1u, &dead);
        __syncthreads();
        if (tid < HID) hh[0][tid] = gload(Hin + tid);        // slot 0
        if (tid == 0) spin_ge(inflag, 2u, &dead);
        __syncthreads();

        unsigned progB_seen = 0;
        for (int t = 0; t < SEQL; ++t) {
            const int cur = t & 1;
            const int slot = t & (QS - 1);
            // issue prefetch of h(t+1) (flag >= t+2 confirmed previous iter)
            float pv = 0.f;
            if (t + 1 < SEQL && tid < HID)
                pv = gload(Hin + (size_t)((t+1) & (QS-1)) * HID + tid);
            unsigned infv = 0xFFFFFFFFu;
            if (tid == 0) infv = uload(inflag);
            // ring back-pressure gate
            if (tid == 0 && (t & 7) == 0 && t + 8 > QS) {
                unsigned need = (unsigned)(t + 8 - QS);
                if (progB_seen < need) progB_seen = spin_ge(consProgB, need, &dead);
            }
            // Wih * h_{l-1}(t): LDS broadcast + register weights
            float acc0 = 0.f, acc1 = 0.f;
            const float4* hb4 = (const float4*)hh[cur];
            #pragma unroll
            for (int i = 0; i < 16; ++i) {
                float4 v = hb4[c4 * 16 + i];
                if (i & 1) {
                    acc1 = fmaf(wi[4*i+0], v.x, acc1); acc1 = fmaf(wi[4*i+1], v.y, acc1);
                    acc1 = fmaf(wi[4*i+2], v.z, acc1); acc1 = fmaf(wi[4*i+3], v.w, acc1);
                } else {
                    acc0 = fmaf(wi[4*i+0], v.x, acc0); acc0 = fmaf(wi[4*i+1], v.y, acc0);
                    acc0 = fmaf(wi[4*i+2], v.z, acc0); acc0 = fmaf(wi[4*i+3], v.w, acc0);
                }
            }
            part[tid] = acc0 + acc1;
            __syncthreads();
            if (tid < HID) {
                float tot = part[tid] + part[tid+256] + part[tid+512] + part[tid+768];
                gstore(Aout + (size_t)slot * HID + tid, tot);
                if (t + 1 < SEQL) hh[cur ^ 1][tid] = pv;
            }
            if (tid == 0) {
                if (t + 2 < SEQL && infv < (unsigned)(t + 3))
                    spin_ge(inflag, (unsigned)(t + 3), &dead);  // for next iter's prefetch
                if ((t & 7) == 7) ustore(myprogA, (unsigned)(t + 1));
            }
            __syncthreads();   // drains IF$ stores before flag
            if (tid == 0) ustore(myflag, (unsigned)(t + 1));
        }
    }
}

// ---------------------------------------------------------------------------
// Kernel 3: out = fc_W @ concat(h0..h3) + fc_b
__global__ __launch_bounds__(1024) void fc_kernel(
    const float* __restrict__ hfinal, const float* __restrict__ fcW,
    const float* __restrict__ fcb, float* __restrict__ out)
{
    __shared__ float red[1024];
    const int tid = threadIdx.x;
    float v  = hfinal[tid];
    float p0 = fcW[tid] * v;
    float p1 = fcW[1024 + tid] * v;

    red[tid] = p0; __syncthreads();
    for (int st = 512; st > 0; st >>= 1) { if (tid < st) red[tid] += red[tid + st]; __syncthreads(); }
    if (tid == 0) out[0] = red[0] + fcb[0];
    __syncthreads();
    red[tid] = p1; __syncthreads();
    for (int st = 512; st > 0; st >>= 1) { if (tid < st) red[tid] += red[tid + st]; __syncthreads(); }
    if (tid == 0) out[1] = red[0] + fcb[1];
}

// ---------------------------------------------------------------------------
extern "C" void kernel_launch(void* const* d_in, const int* in_sizes, int n_in,
                              void* d_out, int out_size, void* d_ws, size_t ws_size,
                              hipStream_t stream)
{
    (void)in_sizes; (void)n_in; (void)out_size; (void)ws_size;
    const float* x        = (const float*)d_in[0];
    const float* lp_Wih0  = (const float*)d_in[1];
    const float* lp_Wih   = (const float*)d_in[2];
    const float* lp_Whh   = (const float*)d_in[3];
    const float* lp_bih   = (const float*)d_in[4];
    const float* lp_bhh   = (const float*)d_in[5];
    const float* lpv_Wih0 = (const float*)d_in[6];
    const float* lpv_Wih  = (const float*)d_in[7];
    const float* lpv_Whh  = (const float*)d_in[8];
    const float* lpv_bih  = (const float*)d_in[9];
    const float* lpv_bhh  = (const float*)d_in[10];
    const float* fcW      = (const float*)d_in[11];
    const float* fcb      = (const float*)d_in[12];

    float* ws      = (float*)d_ws;
    float* Pbuf    = ws + P_OFF;
    float* Hring   = ws + H_OFF;
    float* Apart   = ws + AP_OFF;
    float* hfinal  = ws + HF_OFF;
    unsigned* flags = (unsigned*)(ws + FLAG_OFF_FLOATS);

    hipMemsetAsync(flags, 0, NFLAGS * sizeof(unsigned), stream);

    proj_kernel<<<SEQL / TPB, 1024, 0, stream>>>(x, lp_Wih0, lpv_Wih0, Pbuf);

    rnn_pipe<<<124, 1024, 0, stream>>>(lp_Wih, lp_Whh, lp_bih, lp_bhh,
                                       lpv_Wih, lpv_Whh, lpv_bih, lpv_bhh,
                                       Pbuf, Hring, Apart, hfinal,
                                       flags, flags + 64, flags + 128, flags + 192);

    fc_kernel<<<1, 1024, 0, stream>>>(hfinal, fcW, fcb, (float*)d_out);
}